// Round 1
// baseline (9059.206 us; speedup 1.0000x reference)
//
#include <hip/hip_runtime.h>
#include <hip/hip_bf16.h>

typedef __bf16 bf16x8 __attribute__((ext_vector_type(8)));
typedef float f32x4 __attribute__((ext_vector_type(4)));

__device__ __forceinline__ float fsig(float x){ return 1.0f/(1.0f + __expf(-x)); }
__device__ __forceinline__ float ftanh(float x){ return 1.0f - 2.0f/(__expf(2.0f*x)+1.0f); }

// fp32 -> bf16 (RNE) vectorized converter
__global__ void f2b4(const float4* __restrict__ src, ushort4* __restrict__ dst, int n4){
  int i = blockIdx.x*blockDim.x + threadIdx.x;
  if (i < n4){
    float4 v = src[i];
    __hip_bfloat16 a=__float2bfloat16(v.x), b=__float2bfloat16(v.y), c=__float2bfloat16(v.z), d=__float2bfloat16(v.w);
    ushort4 r;
    r.x = *reinterpret_cast<ushort*>(&a);
    r.y = *reinterpret_cast<ushort*>(&b);
    r.z = *reinterpret_cast<ushort*>(&c);
    r.w = *reinterpret_cast<ushort*>(&d);
    dst[i] = r;
  }
}

// dec_in[m][j] = x[63][m][j], j<2
__global__ void init_decin(const float* __restrict__ x, float* __restrict__ di){
  int i = blockIdx.x*blockDim.x + threadIdx.x;
  if (i < 2048){ int m = i >> 1, j = i & 1; di[i] = x[(size_t)63*4096 + m*4 + j]; }
}

// One LSTM cell: gates = [Ax]@Wih^T + Ah@Whh^T + xs@Ws^T + bih + bhh; pointwise update.
// A matrices: [1024][512] bf16 (ushort). W matrices: [2048][512] bf16. xs: [1024][ks] fp32, Ws: [2048][ks] fp32.
// Grid: (16 batch tiles of 64) x (16 hidden tiles of 32). Block 256 = 4 waves.
// Wave w owns batch rows [w*16, w*16+16), all 4 gates x 32 hidden cols (8 MFMA N-frags).
__global__ __launch_bounds__(256) void lstm_cell(
    const ushort* __restrict__ Ax, const ushort* __restrict__ Wih,
    const ushort* __restrict__ Ah, const ushort* __restrict__ Whh,
    const float* __restrict__ xs, const float* __restrict__ Ws, int ks,
    const float* __restrict__ bih, const float* __restrict__ bhh,
    float* __restrict__ c_st, ushort* __restrict__ h_out)
{
  __shared__ ushort Als[64*64];    // 64 batch rows x 64 k, XOR-swizzled 16B chunks
  __shared__ ushort Bls[128*64];   // 128 gate rows (4 gates x 32 hid) x 64 k

  const int tid = threadIdx.x;
  const int m0 = blockIdx.x * 64;
  const int h0 = blockIdx.y * 32;
  const int w = tid >> 6, lane = tid & 63;
  const int colL = lane & 15, kgrp = lane >> 4;
  const int ar = w*16 + colL;

  f32x4 acc[8] = {};   // acc[g*2 + hc]

  const ushort* Aseg[2] = {Ax, Ah};
  const ushort* Wseg[2] = {Wih, Whh};

  for (int seg = 0; seg < 2; ++seg){
    const ushort* A  = Aseg[seg];
    const ushort* Wt = Wseg[seg];
    if (A == nullptr) continue;
    for (int k0 = 0; k0 < 512; k0 += 64){
      __syncthreads();
      // stage A tile: 64 rows x 8 chunks(16B) = 512 chunks, 2/thread
      #pragma unroll
      for (int it = 0; it < 2; ++it){
        int idx = tid + it*256;
        int r = idx >> 3, cch = idx & 7;
        uint4 v = *reinterpret_cast<const uint4*>(A + (m0 + r)*512 + k0 + cch*8);
        *reinterpret_cast<uint4*>(&Als[r*64 + ((cch ^ (r & 7)) << 3)]) = v;
      }
      // stage B tile: 128 rows x 8 chunks = 1024 chunks, 4/thread
      #pragma unroll
      for (int it = 0; it < 4; ++it){
        int idx = tid + it*256;
        int r = idx >> 3, cch = idx & 7;
        int g = r >> 5, hh = r & 31;
        uint4 v = *reinterpret_cast<const uint4*>(Wt + (g*512 + h0 + hh)*512 + k0 + cch*8);
        *reinterpret_cast<uint4*>(&Bls[r*64 + ((cch ^ (r & 7)) << 3)]) = v;
      }
      __syncthreads();
      #pragma unroll
      for (int kh = 0; kh < 2; ++kh){
        int cb = (kh << 2) + kgrp;   // k-chunk index for this lane
        bf16x8 av = *reinterpret_cast<const bf16x8*>(&Als[ar*64 + ((cb ^ (ar & 7)) << 3)]);
        #pragma unroll
        for (int nf = 0; nf < 8; ++nf){
          int br = nf*16 + colL;
          bf16x8 bv = *reinterpret_cast<const bf16x8*>(&Bls[br*64 + ((cb ^ (br & 7)) << 3)]);
          acc[nf] = __builtin_amdgcn_mfma_f32_16x16x32_bf16(av, bv, acc[nf], 0, 0, 0);
        }
      }
    }
  }

  // epilogue: small-K x contribution (fp32), bias, gates, cell update
  float xsv[4][4];
  if (ks > 0){
    #pragma unroll
    for (int reg = 0; reg < 4; ++reg){
      int m = m0 + w*16 + kgrp*4 + reg;
      #pragma unroll
      for (int k = 0; k < 4; ++k) xsv[reg][k] = (k < ks) ? xs[m*ks + k] : 0.0f;
    }
  }
  #pragma unroll
  for (int hc = 0; hc < 2; ++hc){
    int h = h0 + hc*16 + colL;
    float bia[4], wsv[4][4];
    #pragma unroll
    for (int g = 0; g < 4; ++g){
      int n = g*512 + h;
      bia[g] = bih[n] + bhh[n];
      if (ks > 0){
        #pragma unroll
        for (int k = 0; k < 4; ++k) wsv[g][k] = (k < ks) ? Ws[n*ks + k] : 0.0f;
      }
    }
    #pragma unroll
    for (int reg = 0; reg < 4; ++reg){
      int m = m0 + w*16 + kgrp*4 + reg;
      float gv[4];
      #pragma unroll
      for (int g = 0; g < 4; ++g){
        float t_ = acc[g*2+hc][reg] + bia[g];
        if (ks > 0){
          #pragma unroll
          for (int k = 0; k < 4; ++k) t_ += xsv[reg][k]*wsv[g][k];
        }
        gv[g] = t_;
      }
      float iG = fsig(gv[0]);
      float fG = fsig(gv[1]);
      float gG = ftanh(gv[2]);
      float oG = fsig(gv[3]);
      int off = m*512 + h;
      float cn = fG * c_st[off] + iG * gG;
      c_st[off] = cn;
      float hv = oG * ftanh(cn);
      __hip_bfloat16 hb = __float2bfloat16(hv);
      h_out[off] = *reinterpret_cast<ushort*>(&hb);
    }
  }
}

// out[m][j] = sum_h h2[m][h]*linW[j][h] + linb[j]; writes d_out slice and dec_in (fp32)
__global__ __launch_bounds__(256) void dec_linear(const ushort* __restrict__ h2,
    const float* __restrict__ linW, const float* __restrict__ linb,
    float* __restrict__ outp, float* __restrict__ di){
  int tid = threadIdx.x, w = tid >> 6, lane = tid & 63;
  int mbase = blockIdx.x*32 + w*8;
  for (int r = 0; r < 8; ++r){
    int m = mbase + r;
    float p0 = 0.f, p1 = 0.f;
    #pragma unroll
    for (int kk = 0; kk < 8; ++kk){
      int k = lane + kk*64;
      float hv = __uint_as_float(((unsigned)h2[m*512 + k]) << 16);
      p0 += hv * linW[k];
      p1 += hv * linW[512 + k];
    }
    #pragma unroll
    for (int off = 32; off > 0; off >>= 1){
      p0 += __shfl_down(p0, off);
      p1 += __shfl_down(p1, off);
    }
    if (lane == 0){
      float o0 = p0 + linb[0], o1 = p1 + linb[1];
      outp[m*2]   = o0; outp[m*2+1] = o1;
      di[m*2]     = o0; di[m*2+1]   = o1;
    }
  }
}

extern "C" void kernel_launch(void* const* d_in, const int* in_sizes, int n_in,
                              void* d_out, int out_size, void* d_ws, size_t ws_size,
                              hipStream_t stream)
{
  const float* x        = (const float*)d_in[0];
  const float* enc_Wih0 = (const float*)d_in[1];
  const float* enc_Whh0 = (const float*)d_in[2];
  const float* enc_bih0 = (const float*)d_in[3];
  const float* enc_bhh0 = (const float*)d_in[4];
  const float* enc_Wih  = (const float*)d_in[5];
  const float* enc_Whh  = (const float*)d_in[6];
  const float* enc_bih  = (const float*)d_in[7];
  const float* enc_bhh  = (const float*)d_in[8];
  const float* dec_Wih0 = (const float*)d_in[9];
  const float* dec_Whh0 = (const float*)d_in[10];
  const float* dec_bih0 = (const float*)d_in[11];
  const float* dec_bhh0 = (const float*)d_in[12];
  const float* dec_Wih  = (const float*)d_in[13];
  const float* dec_Whh  = (const float*)d_in[14];
  const float* dec_bih  = (const float*)d_in[15];
  const float* dec_bhh  = (const float*)d_in[16];
  const float* lin_W    = (const float*)d_in[17];
  const float* lin_b    = (const float*)d_in[18];

  const size_t W  = (size_t)2048*512;   // weight elems
  const size_t HS = (size_t)1024*512;   // h/c slot elems
  ushort* wb    = (ushort*)d_ws;
  ushort* eWhh0 = wb;
  ushort* eWih  = wb + W;
  ushort* eWhh  = wb + 3*W;
  ushort* dWhh0 = wb + 5*W;
  ushort* dWih  = wb + 6*W;
  ushort* dWhh  = wb + 8*W;
  ushort* hbuf  = wb + 10*W;            // 3 layers x 2 slots, bf16
  float*  cbuf  = (float*)(hbuf + 6*HS);
  float*  dec_in = cbuf + 3*HS;         // 1024 x 2 fp32
  // ws required ~ 33.6 MB

  hipMemsetAsync(hbuf, 0, 6*HS*2 + 3*HS*4 + 2048*4, stream);

  const int thr = 256;
  {
    struct { const float* s; ushort* d; size_t n; } cv[6] = {
      {enc_Whh0, eWhh0, W}, {enc_Wih, eWih, 2*W}, {enc_Whh, eWhh, 2*W},
      {dec_Whh0, dWhh0, W}, {dec_Wih, dWih, 2*W}, {dec_Whh, dWhh, 2*W},
    };
    for (int i = 0; i < 6; ++i){
      int n4 = (int)(cv[i].n/4);
      f2b4<<<(n4+thr-1)/thr, thr, 0, stream>>>((const float4*)cv[i].s, (ushort4*)cv[i].d, n4);
    }
  }

  dim3 cgrid(16,16), cblk(256);
  auto hptr = [&](int l, int s){ return hbuf + ((size_t)l*2 + s)*HS; };
  auto cptr = [&](int l){ return cbuf + (size_t)l*HS; };

  // ---- encoder (wavefront order: layer l at step s handles t = s-l) ----
  for (int s = 0; s < 66; ++s){
    for (int l = 0; l < 3; ++l){
      int t = s - l;
      if (t < 0 || t >= 64) continue;
      ushort* hout = hptr(l, s & 1);
      const ushort* Ahp = hptr(l, (s & 1) ^ 1);
      if (l == 0){
        lstm_cell<<<cgrid, cblk, 0, stream>>>(nullptr, nullptr, Ahp, eWhh0,
            x + (size_t)t*1024*4, enc_Wih0, 4, enc_bih0, enc_bhh0, cptr(0), hout);
      } else {
        lstm_cell<<<cgrid, cblk, 0, stream>>>(hptr(l-1, (s & 1) ^ 1), eWih + (size_t)(l-1)*W,
            Ahp, eWhh + (size_t)(l-1)*W, nullptr, nullptr, 0,
            enc_bih + (l-1)*2048, enc_bhh + (l-1)*2048, cptr(l), hout);
      }
    }
  }

  // ---- decoder ----
  init_decin<<<8, 256, 0, stream>>>(x, dec_in);
  int cur[3] = {1, 0, 1};   // slots holding encoder-final h per layer: (63+l)&1
  for (int t = 0; t < 32; ++t){
    lstm_cell<<<cgrid, cblk, 0, stream>>>(nullptr, nullptr, hptr(0,cur[0]), dWhh0,
        dec_in, dec_Wih0, 2, dec_bih0, dec_bhh0, cptr(0), hptr(0, cur[0]^1));
    cur[0] ^= 1;
    lstm_cell<<<cgrid, cblk, 0, stream>>>(hptr(0,cur[0]), dWih,
        hptr(1,cur[1]), dWhh, nullptr, nullptr, 0,
        dec_bih, dec_bhh, cptr(1), hptr(1, cur[1]^1));
    cur[1] ^= 1;
    lstm_cell<<<cgrid, cblk, 0, stream>>>(hptr(1,cur[1]), dWih + W,
        hptr(2,cur[2]), dWhh + W, nullptr, nullptr, 0,
        dec_bih + 2048, dec_bhh + 2048, cptr(2), hptr(2, cur[2]^1));
    cur[2] ^= 1;
    dec_linear<<<32, 256, 0, stream>>>(hptr(2,cur[2]), lin_W, lin_b,
        (float*)d_out + (size_t)t*2048, dec_in);
  }
}

// Round 2
// 2798.522 us; speedup vs baseline: 3.2371x; 3.2371x over previous
//
#include <hip/hip_runtime.h>
#include <hip/hip_bf16.h>

typedef __bf16 bf16x8 __attribute__((ext_vector_type(8)));
typedef float f32x4 __attribute__((ext_vector_type(4)));

#define HSZ (1024*512)      // h/c slot elems
#define WSZ (2048*512)      // weight matrix elems

__device__ __forceinline__ float fsig(float x){ return 1.0f/(1.0f+__expf(-x)); }
__device__ __forceinline__ float ftanh(float x){ return 1.0f - 2.0f/(__expf(2.0f*x)+1.0f); }

__device__ __forceinline__ void gload16(const void* g, void* l){
  __builtin_amdgcn_global_load_lds((const __attribute__((address_space(1))) void*)g,
                                   (__attribute__((address_space(3))) void*)l, 16, 0, 0);
}

// fp32 -> bf16 (RNE) converter
__global__ void f2b4(const float4* __restrict__ src, ushort4* __restrict__ dst, int n4){
  int i = blockIdx.x*blockDim.x + threadIdx.x;
  if (i < n4){
    float4 v = src[i];
    __hip_bfloat16 a=__float2bfloat16(v.x), b=__float2bfloat16(v.y), c=__float2bfloat16(v.z), d=__float2bfloat16(v.w);
    ushort4 r;
    r.x = *reinterpret_cast<ushort*>(&a);
    r.y = *reinterpret_cast<ushort*>(&b);
    r.z = *reinterpret_cast<ushort*>(&c);
    r.w = *reinterpret_cast<ushort*>(&d);
    dst[i] = r;
  }
}

__global__ void init_decin(const float* __restrict__ x, float* __restrict__ di){
  int i = blockIdx.x*blockDim.x + threadIdx.x;
  if (i < 2048){ int m = i >> 1, j = i & 1; di[i] = x[(size_t)63*4096 + m*4 + j]; }
}

// Wcomb[n][k] = dec_Wih0[n][0]*lin_W[0][k] + dec_Wih0[n][1]*lin_W[1][k]  (bf16)
__global__ void make_wcomb(const float* __restrict__ dWih0, const float* __restrict__ linW,
                           ushort* __restrict__ wc){
  int i = blockIdx.x*blockDim.x + threadIdx.x;
  if (i < 2048*512){
    int n = i >> 9, k = i & 511;
    float v = dWih0[n*2]*linW[k] + dWih0[n*2+1]*linW[512+k];
    __hip_bfloat16 b = __float2bfloat16(v);
    wc[i] = *reinterpret_cast<ushort*>(&b);
  }
}

// combined biases: rows 0-2 enc l0-l2; 3 dec l0 (t=0); 4 dec l0 (t>=1, +Wih0@lin_b); 5,6 dec l1,l2
__global__ void prep_bias(const float* ebih0, const float* ebhh0,
                          const float* ebih, const float* ebhh,
                          const float* dbih0, const float* dbhh0,
                          const float* dbih, const float* dbhh,
                          const float* dWih0, const float* linb, float* bout){
  int n = blockIdx.x*blockDim.x + threadIdx.x;
  if (n >= 2048) return;
  bout[n]        = ebih0[n] + ebhh0[n];
  bout[2048+n]   = ebih[n] + ebhh[n];
  bout[2*2048+n] = ebih[2048+n] + ebhh[2048+n];
  float d0 = dbih0[n] + dbhh0[n];
  bout[3*2048+n] = d0;
  bout[4*2048+n] = d0 + dWih0[n*2]*linb[0] + dWih0[n*2+1]*linb[1];
  bout[5*2048+n] = dbih[n] + dbhh[n];
  bout[6*2048+n] = dbih[2048+n] + dbhh[2048+n];
}

struct CellPar {
  const ushort* A0; const ushort* W0;   // bf16 segment 0 (A:[1024][512], W:[2048][512])
  const ushort* A1; const ushort* W1;   // bf16 segment 1 (null if absent)
  const float*  xs; const float* Ws; int ks;  // small-K fp32 part
  const float*  bias;                   // combined bias [2048]
  float* c; ushort* h_out;
};

// tile: 64 batch x (4 gates x 16 hid). grid (16,32). 256 threads = 4 waves.
// 2-phase pipeline, global_load_lds w16, XOR-swizzled (pre-swizzled source).
__device__ __forceinline__ void cell_body(const CellPar P, char* ldsb)
{
  const int tid  = threadIdx.x;
  const int m0   = blockIdx.x << 6;
  const int h0   = blockIdx.y << 4;
  const int w    = tid >> 6, lane = tid & 63;
  const int colL = lane & 15, kgrp = lane >> 4;
  const int srow = lane >> 3, scch = lane & 7;

  const ushort* Aseg[2] = { P.A0, P.A1 };
  const ushort* Wseg[2] = { P.W0, P.W1 };
  const int nt = (P.A1 != nullptr) ? 16 : 8;   // 8 k0-iters per 512-K segment

  auto stage = [&](int buf, int it){
    const int seg = it >> 3;
    const int k0  = (it & 7) << 6;
    const ushort* A  = Aseg[seg];
    const ushort* Wt = Wseg[seg];
    ushort* Als = (ushort*)(ldsb + buf*16384);
    ushort* Bls = Als + 64*64;
    #pragma unroll
    for (int half = 0; half < 2; ++half){
      const int r  = (w<<4) + (half<<3) + srow;     // tile row (A: batch, B: g*16+hh)
      const int sw = (scch ^ (r & 7)) << 3;         // pre-swizzled source chunk
      const ushort* ga = A + (size_t)(m0 + r)*512 + k0 + sw;
      gload16(ga, Als + ((w<<4) + (half<<3))*64);
      const int hh = (half<<3) + srow;              // gate g = w
      const ushort* gb = Wt + ((size_t)(w<<9) + h0 + hh)*512 + k0 + sw;
      gload16(gb, Bls + ((w<<4) + (half<<3))*64);
    }
  };

  f32x4 acc[4] = {};

  stage(0, 0);
  for (int it = 0; it < nt; ++it){
    const int cur = it & 1;
    if (it + 1 < nt) stage(cur ^ 1, it + 1);
    __builtin_amdgcn_sched_barrier(0);
    if (it + 1 < nt) asm volatile("s_waitcnt vmcnt(4)" ::: "memory");
    else             asm volatile("s_waitcnt vmcnt(0)" ::: "memory");
    __builtin_amdgcn_s_barrier();                  // all waves' stage(it) landed
    __builtin_amdgcn_sched_barrier(0);
    const ushort* Als = (const ushort*)(ldsb + cur*16384);
    const ushort* Bls = Als + 64*64;
    const int ar = (w<<4) + colL;
    #pragma unroll
    for (int kh = 0; kh < 2; ++kh){
      const int cb = (kh<<2) + kgrp;
      bf16x8 av = *(const bf16x8*)(Als + ar*64 + ((cb ^ (ar & 7)) << 3));
      #pragma unroll
      for (int nf = 0; nf < 4; ++nf){
        const int br = (nf<<4) + colL;
        bf16x8 bv = *(const bf16x8*)(Bls + br*64 + ((cb ^ (br & 7)) << 3));
        acc[nf] = __builtin_amdgcn_mfma_f32_16x16x32_bf16(av, bv, acc[nf], 0, 0, 0);
      }
    }
    __builtin_amdgcn_sched_barrier(0);
    __builtin_amdgcn_s_barrier();                  // reads done before buffer reuse
  }

  // epilogue
  const int h  = h0 + colL;
  const int mB = m0 + (w<<4) + (kgrp<<2);

  float xsv[4][4], wsv[4][4];
  if (P.ks > 0){
    #pragma unroll
    for (int r = 0; r < 4; ++r)
      #pragma unroll
      for (int k = 0; k < 4; ++k)
        xsv[r][k] = (k < P.ks) ? P.xs[(size_t)(mB + r)*P.ks + k] : 0.f;
    #pragma unroll
    for (int g = 0; g < 4; ++g)
      #pragma unroll
      for (int k = 0; k < 4; ++k)
        wsv[g][k] = (k < P.ks) ? P.Ws[(size_t)((g<<9) + h)*P.ks + k] : 0.f;
  }
  float bia[4];
  #pragma unroll
  for (int g = 0; g < 4; ++g) bia[g] = P.bias[(g<<9) + h];

  #pragma unroll
  for (int r = 0; r < 4; ++r){
    const int m = mB + r;
    float gv[4];
    #pragma unroll
    for (int g = 0; g < 4; ++g){
      float t_ = acc[g][r] + bia[g];
      if (P.ks > 0){
        #pragma unroll
        for (int k = 0; k < 4; ++k) t_ += xsv[r][k]*wsv[g][k];
      }
      gv[g] = t_;
    }
    const float iG = fsig(gv[0]);
    const float fG = fsig(gv[1]);
    const float gG = ftanh(gv[2]);
    const float oG = fsig(gv[3]);
    const size_t off = (size_t)m*512 + h;
    const float cn = fG*P.c[off] + iG*gG;
    P.c[off] = cn;
    const float hv = oG*ftanh(cn);
    __hip_bfloat16 hb = __float2bfloat16(hv);
    P.h_out[off] = *reinterpret_cast<const ushort*>(&hb);
  }
}

__global__ __launch_bounds__(256) void cell_k(CellPar P){
  __shared__ char lds[32768];
  cell_body(P, lds);
}

struct EncPack {
  const float* x; const float* Wih0f;
  const ushort* eWhh0; const ushort* eWih; const ushort* eWhh;
  const float* biases; ushort* hbuf; float* cbuf; int s;
};

// fused encoder wavefront step: blockIdx.z = layer, t = s - l
__global__ __launch_bounds__(256) void enc_step(EncPack E){
  __shared__ char lds[32768];
  const int l = blockIdx.z;
  const int t = E.s - l;
  if (t < 0 || t > 63) return;
  const int p = E.s & 1;
  CellPar P;
  if (l == 0){
    P = { E.hbuf + (size_t)(p^1)*HSZ, E.eWhh0,
          nullptr, nullptr,
          E.x + (size_t)t*4096, E.Wih0f, 4,
          E.biases, E.cbuf, E.hbuf + (size_t)p*HSZ };
  } else {
    P = { E.hbuf + (size_t)(2*(l-1) + (p^1))*HSZ, E.eWih + (size_t)(l-1)*WSZ,
          E.hbuf + (size_t)(2*l + (p^1))*HSZ,     E.eWhh + (size_t)(l-1)*WSZ,
          nullptr, nullptr, 0,
          E.biases + l*2048, E.cbuf + (size_t)l*HSZ, E.hbuf + (size_t)(2*l + p)*HSZ };
  }
  cell_body(P, lds);
}

// batched final linear over all 32 steps: rows = 32*1024
__global__ __launch_bounds__(256) void out_linear(const ushort* __restrict__ h2,
    const float* __restrict__ linW, const float* __restrict__ linb, float* __restrict__ outp){
  int tid = threadIdx.x, w = tid >> 6, lane = tid & 63;
  int rbase = blockIdx.x*32 + w*8;
  for (int r = 0; r < 8; ++r){
    int m = rbase + r;
    float p0 = 0.f, p1 = 0.f;
    #pragma unroll
    for (int kk = 0; kk < 8; ++kk){
      int k = lane + kk*64;
      float hv = __uint_as_float(((unsigned)h2[(size_t)m*512 + k]) << 16);
      p0 += hv * linW[k];
      p1 += hv * linW[512 + k];
    }
    #pragma unroll
    for (int off = 32; off > 0; off >>= 1){
      p0 += __shfl_down(p0, off);
      p1 += __shfl_down(p1, off);
    }
    if (lane == 0){
      outp[(size_t)m*2]   = p0 + linb[0];
      outp[(size_t)m*2+1] = p1 + linb[1];
    }
  }
}

// fallback per-step linear (small-ws path): writes out slice + dec_in
__global__ __launch_bounds__(256) void dec_linear(const ushort* __restrict__ h2,
    const float* __restrict__ linW, const float* __restrict__ linb,
    float* __restrict__ outp, float* __restrict__ di){
  int tid = threadIdx.x, w = tid >> 6, lane = tid & 63;
  int mbase = blockIdx.x*32 + w*8;
  for (int r = 0; r < 8; ++r){
    int m = mbase + r;
    float p0 = 0.f, p1 = 0.f;
    #pragma unroll
    for (int kk = 0; kk < 8; ++kk){
      int k = lane + kk*64;
      float hv = __uint_as_float(((unsigned)h2[(size_t)m*512 + k]) << 16);
      p0 += hv * linW[k];
      p1 += hv * linW[512 + k];
    }
    #pragma unroll
    for (int off = 32; off > 0; off >>= 1){
      p0 += __shfl_down(p0, off);
      p1 += __shfl_down(p1, off);
    }
    if (lane == 0){
      float o0 = p0 + linb[0], o1 = p1 + linb[1];
      outp[m*2]   = o0; outp[m*2+1] = o1;
      di[m*2]     = o0; di[m*2+1]   = o1;
    }
  }
}

extern "C" void kernel_launch(void* const* d_in, const int* in_sizes, int n_in,
                              void* d_out, int out_size, void* d_ws, size_t ws_size,
                              hipStream_t stream)
{
  const float* x        = (const float*)d_in[0];
  const float* enc_Wih0 = (const float*)d_in[1];
  const float* enc_Whh0 = (const float*)d_in[2];
  const float* enc_bih0 = (const float*)d_in[3];
  const float* enc_bhh0 = (const float*)d_in[4];
  const float* enc_Wih  = (const float*)d_in[5];
  const float* enc_Whh  = (const float*)d_in[6];
  const float* enc_bih  = (const float*)d_in[7];
  const float* enc_bhh  = (const float*)d_in[8];
  const float* dec_Wih0 = (const float*)d_in[9];
  const float* dec_Whh0 = (const float*)d_in[10];
  const float* dec_bih0 = (const float*)d_in[11];
  const float* dec_bhh0 = (const float*)d_in[12];
  const float* dec_Wih  = (const float*)d_in[13];
  const float* dec_Whh  = (const float*)d_in[14];
  const float* dec_bih  = (const float*)d_in[15];
  const float* dec_bhh  = (const float*)d_in[16];
  const float* lin_W    = (const float*)d_in[17];
  const float* lin_b    = (const float*)d_in[18];

  // big path needs: 2*(11W + 6HS + 32HS) + 4*(3HS + 2048 + 7*2048) bytes = 69,271,552
  const bool big = ws_size >= 69271552ull;

  ushort* wb     = (ushort*)d_ws;
  ushort* eWhh0b = wb;
  ushort* eWihb  = wb + (size_t)WSZ;
  ushort* eWhhb  = wb + 3*(size_t)WSZ;
  ushort* dWhh0b = wb + 5*(size_t)WSZ;
  ushort* dWihb  = wb + 6*(size_t)WSZ;
  ushort* dWhhb  = wb + 8*(size_t)WSZ;
  ushort* wcombb = wb + 10*(size_t)WSZ;                   // big only
  ushort* hbuf   = wb + (big ? 11 : 10)*(size_t)WSZ;      // 6 HSZ (3 layers x 2 slots)
  ushort* h2hist = hbuf + 6*(size_t)HSZ;                  // big: 32 HSZ
  float*  cbuf   = (float*)(h2hist + (big ? 32*(size_t)HSZ : 0));
  float*  dec_in = cbuf + 3*(size_t)HSZ;                  // 2048
  float*  biases = dec_in + 2048;                         // 7*2048

  hipMemsetAsync(hbuf, 0, 6*(size_t)HSZ*2, stream);
  hipMemsetAsync(cbuf, 0, 3*(size_t)HSZ*4, stream);

  const int thr = 256;
  {
    struct { const float* s; ushort* d; size_t n; } cv[6] = {
      {enc_Whh0, eWhh0b, WSZ}, {enc_Wih, eWihb, 2*(size_t)WSZ}, {enc_Whh, eWhhb, 2*(size_t)WSZ},
      {dec_Whh0, dWhh0b, WSZ}, {dec_Wih, dWihb, 2*(size_t)WSZ}, {dec_Whh, dWhhb, 2*(size_t)WSZ},
    };
    for (int i = 0; i < 6; ++i){
      int n4 = (int)(cv[i].n/4);
      f2b4<<<(n4+thr-1)/thr, thr, 0, stream>>>((const float4*)cv[i].s, (ushort4*)cv[i].d, n4);
    }
  }
  if (big) make_wcomb<<<4096, thr, 0, stream>>>(dec_Wih0, lin_W, wcombb);
  prep_bias<<<8, thr, 0, stream>>>(enc_bih0, enc_bhh0, enc_bih, enc_bhh,
                                   dec_bih0, dec_bhh0, dec_bih, dec_bhh,
                                   dec_Wih0, lin_b, biases);
  init_decin<<<8, thr, 0, stream>>>(x, dec_in);

  const dim3 cgrid(16, 32), cblk(256);

  // ---- encoder: fused wavefront steps ----
  for (int s = 0; s < 66; ++s){
    EncPack E = { x, enc_Wih0, eWhh0b, eWihb, eWhhb, biases, hbuf, cbuf, s };
    enc_step<<<dim3(16,32,3), cblk, 0, stream>>>(E);
  }

  // encoder-final slots: layer l written at step 63+l -> slot (63+l)&1
  int cur0 = 1, cur1 = 0, cur2 = 1;

  if (big){
    for (int t = 0; t < 32; ++t){
      CellPar P0;
      if (t == 0)
        P0 = { hbuf + (size_t)cur0*HSZ, dWhh0b, nullptr, nullptr,
               dec_in, dec_Wih0, 2, biases + 3*2048, cbuf, hbuf + (size_t)(cur0^1)*HSZ };
      else
        P0 = { h2hist + (size_t)(t-1)*HSZ, wcombb, hbuf + (size_t)cur0*HSZ, dWhh0b,
               nullptr, nullptr, 0, biases + 4*2048, cbuf, hbuf + (size_t)(cur0^1)*HSZ };
      cell_k<<<cgrid, cblk, 0, stream>>>(P0); cur0 ^= 1;

      CellPar P1 = { hbuf + (size_t)cur0*HSZ, dWihb, hbuf + (size_t)(2+cur1)*HSZ, dWhhb,
                     nullptr, nullptr, 0, biases + 5*2048, cbuf + (size_t)HSZ,
                     hbuf + (size_t)(2+(cur1^1))*HSZ };
      cell_k<<<cgrid, cblk, 0, stream>>>(P1); cur1 ^= 1;

      const ushort* a2prev = (t == 0) ? (hbuf + (size_t)(4+1)*HSZ) : (h2hist + (size_t)(t-1)*HSZ);
      CellPar P2 = { hbuf + (size_t)(2+cur1)*HSZ, dWihb + (size_t)WSZ, a2prev, dWhhb + (size_t)WSZ,
                     nullptr, nullptr, 0, biases + 6*2048, cbuf + 2*(size_t)HSZ,
                     h2hist + (size_t)t*HSZ };
      cell_k<<<cgrid, cblk, 0, stream>>>(P2);
    }
    out_linear<<<1024, cblk, 0, stream>>>(h2hist, lin_W, lin_b, (float*)d_out);
  } else {
    for (int t = 0; t < 32; ++t){
      CellPar P0 = { hbuf + (size_t)cur0*HSZ, dWhh0b, nullptr, nullptr,
                     dec_in, dec_Wih0, 2, biases + 3*2048, cbuf, hbuf + (size_t)(cur0^1)*HSZ };
      cell_k<<<cgrid, cblk, 0, stream>>>(P0); cur0 ^= 1;

      CellPar P1 = { hbuf + (size_t)cur0*HSZ, dWihb, hbuf + (size_t)(2+cur1)*HSZ, dWhhb,
                     nullptr, nullptr, 0, biases + 5*2048, cbuf + (size_t)HSZ,
                     hbuf + (size_t)(2+(cur1^1))*HSZ };
      cell_k<<<cgrid, cblk, 0, stream>>>(P1); cur1 ^= 1;

      CellPar P2 = { hbuf + (size_t)(2+cur1)*HSZ, dWihb + (size_t)WSZ,
                     hbuf + (size_t)(4+cur2)*HSZ, dWhhb + (size_t)WSZ,
                     nullptr, nullptr, 0, biases + 6*2048, cbuf + 2*(size_t)HSZ,
                     hbuf + (size_t)(4+(cur2^1))*HSZ };
      cell_k<<<cgrid, cblk, 0, stream>>>(P2); cur2 ^= 1;

      dec_linear<<<32, cblk, 0, stream>>>(hbuf + (size_t)(4+cur2)*HSZ, lin_W, lin_b,
                                          (float*)d_out + (size_t)t*2048, dec_in);
    }
  }
}